// Round 1
// baseline (610.669 us; speedup 1.0000x reference)
//
#include <hip/hip_runtime.h>

// Transformer block forward, MI355X gfx950.
// B=4, T=2048, D=1024, H=16, DH=64. bf16 MFMA compute, f32 accum/residuals.

#define B_ 4
#define T_ 2048
#define D_ 1024
#define H_ 16
#define DH_ 64

using u16 = unsigned short;
typedef short bf16x8 __attribute__((ext_vector_type(8)));   // 8 bf16 (4 VGPRs)
typedef float f32x4 __attribute__((ext_vector_type(4)));

#define GLOAD_LDS16(g, l)                                                          \
  __builtin_amdgcn_global_load_lds((const __attribute__((address_space(1))) void*)(g), \
                                   (__attribute__((address_space(3))) void*)(l), 16, 0, 0)

__device__ __forceinline__ f32x4 mfma16(bf16x8 a, bf16x8 b, f32x4 c) {
  return __builtin_amdgcn_mfma_f32_16x16x32_bf16(a, b, c, 0, 0, 0);
}

__device__ __forceinline__ u16 f2bf(float f) {  // RNE f32->bf16
  union { float f; unsigned u; } v; v.f = f;
  unsigned r = v.u + 0x7fffu + ((v.u >> 16) & 1u);
  return (u16)(r >> 16);
}

// ---------------- LayerNorm: x[row][1024] -> f32 + bf16 ----------------
__global__ __launch_bounds__(256)
void ln_kernel(const float* __restrict__ x, const float* __restrict__ g,
               const float* __restrict__ be, float* __restrict__ yf,
               u16* __restrict__ yb)
{
  const int row = blockIdx.x;
  const int tid = threadIdx.x;
  const float4 vx = ((const float4*)(x + (size_t)row * D_))[tid];
  float s  = vx.x + vx.y + vx.z + vx.w;
  float s2 = vx.x*vx.x + vx.y*vx.y + vx.z*vx.z + vx.w*vx.w;
#pragma unroll
  for (int m = 1; m < 64; m <<= 1) { s += __shfl_xor(s, m); s2 += __shfl_xor(s2, m); }
  __shared__ float red[8];
  const int w = tid >> 6;
  if ((tid & 63) == 0) { red[w] = s; red[4 + w] = s2; }
  __syncthreads();
  s  = red[0] + red[1] + red[2] + red[3];
  s2 = red[4] + red[5] + red[6] + red[7];
  const float mu   = s * (1.0f / D_);
  const float rstd = rsqrtf(s2 * (1.0f / D_) - mu * mu + 1e-5f);
  const float4 gg = ((const float4*)g)[tid];
  const float4 bb = ((const float4*)be)[tid];
  float4 y;
  y.x = (vx.x - mu) * rstd * gg.x + bb.x;
  y.y = (vx.y - mu) * rstd * gg.y + bb.y;
  y.z = (vx.z - mu) * rstd * gg.z + bb.z;
  y.w = (vx.w - mu) * rstd * gg.w + bb.w;
  ((float4*)(yf + (size_t)row * D_))[tid] = y;
  ushort4 pk;
  pk.x = f2bf(y.x); pk.y = f2bf(y.y); pk.z = f2bf(y.z); pk.w = f2bf(y.w);
  ((ushort4*)(yb + (size_t)row * D_))[tid] = pk;
}

// ------------- transpose + cvt: in f32 [R][C] -> out bf16 [C][R], per z-matrix -------------
__global__ __launch_bounds__(256)
void transpose_cvt(const float* __restrict__ in, u16* __restrict__ out, int R, int C)
{
  __shared__ float tile[32][33];
  const int c0 = blockIdx.x * 32, r0 = blockIdx.y * 32;
  const float* ip = in + (size_t)blockIdx.z * R * C;
  u16* op = out + (size_t)blockIdx.z * R * C;
  const int tx = threadIdx.x, ty = threadIdx.y;  // 32 x 8
#pragma unroll
  for (int j = 0; j < 4; ++j)
    tile[ty + j * 8][tx] = ip[(size_t)(r0 + ty + j * 8) * C + (c0 + tx)];
  __syncthreads();
#pragma unroll
  for (int j = 0; j < 4; ++j)
    op[(size_t)(c0 + ty + j * 8) * R + (r0 + tx)] = f2bf(tile[tx][ty + j * 8]);
}

// ---------------- GEMM: C[M,N] = A[M,K](bf16) * Bt[N,K]^T(bf16), m97 structure ----------------
#define MODE_QKV 0
#define MODE_WP 1
#define MODE_MLP1 2
#define MODE_MLP2 3

template<int MODE>
__global__ __launch_bounds__(256, 2)
void gemm_kernel(const u16* __restrict__ A, const u16* __restrict__ Bt,
                 int M, int N, int K,
                 const float* __restrict__ bias, const float* __restrict__ resid,
                 float* __restrict__ outf, u16* __restrict__ outb,
                 u16* __restrict__ qo, u16* __restrict__ ko, u16* __restrict__ vo)
{
  __shared__ __align__(16) u16 As[128 * 32];
  __shared__ __align__(16) u16 Bs[128 * 32];
  const int t = threadIdx.x;
  const int w = t >> 6, l = t & 63, lg = l >> 4, lr = l & 15;
  const int wr = w >> 1, wc = w & 1;
  const int bm0 = blockIdx.y * 128, bn0 = blockIdx.x * 128;

  f32x4 acc[4][4] = {};

  // staging: 64B rows [128][32] -> naturally bank-balanced for ds_read_b128
  const int srcCol = (t & 3) << 3;
  const u16* gA = A  + (size_t)(bm0 + (t >> 2)) * K + srcCol;
  const u16* gB = Bt + (size_t)(bn0 + (t >> 2)) * K + srcCol;
  u16* lA = &As[w * 512];
  u16* lB = &Bs[w * 512];
  const size_t skip = (size_t)64 * K;

  for (int kt = 0; kt < K; kt += 32) {
    __syncthreads();
    GLOAD_LDS16(gA + kt,        lA);
    GLOAD_LDS16(gA + skip + kt, lA + 2048);
    GLOAD_LDS16(gB + kt,        lB);
    GLOAD_LDS16(gB + skip + kt, lB + 2048);
    __syncthreads();
    bf16x8 af[4], bfv[4];
#pragma unroll
    for (int m = 0; m < 4; ++m)
      af[m] = *(const bf16x8*)&As[(wr * 64 + m * 16 + lr) * 32 + lg * 8];
#pragma unroll
    for (int n = 0; n < 4; ++n)
      bfv[n] = *(const bf16x8*)&Bs[(wc * 64 + n * 16 + lr) * 32 + lg * 8];
#pragma unroll
    for (int m = 0; m < 4; ++m)
#pragma unroll
      for (int n = 0; n < 4; ++n)
        acc[m][n] = mfma16(af[m], bfv[n], acc[m][n]);
  }

#pragma unroll
  for (int m = 0; m < 4; ++m) {
#pragma unroll
    for (int n = 0; n < 4; ++n) {
#pragma unroll
      for (int r = 0; r < 4; ++r) {
        const int row = bm0 + wr * 64 + m * 16 + lg * 4 + r;   // C row = (lane>>4)*4+reg
        const int col = bn0 + wc * 64 + n * 16 + lr;           // C col = lane&15
        float v = acc[m][n][r];
        if constexpr (MODE == MODE_QKV) {
          const int sel = col >> 10, hh = (col >> 6) & 15, dh = col & 63;
          const int bi = row >> 11, tt = row & 2047;
          u16* dst = (sel == 0) ? qo : (sel == 1) ? ko : vo;
          dst[(((size_t)bi * H_ + hh) * T_ + tt) * DH_ + dh] = f2bf(v);
        } else if constexpr (MODE == MODE_WP) {
          outf[(size_t)row * N + col] = v + bias[col] + resid[(size_t)row * N + col];
        } else if constexpr (MODE == MODE_MLP1) {
          v += bias[col];
          outb[(size_t)row * N + col] = f2bf(v > 0.f ? v : 0.f);
        } else {  // MLP2
          outf[(size_t)row * N + col] = v + bias[col] + resid[(size_t)row * N + col];
        }
      }
    }
  }
}

// ---------------- Flash attention, causal, 64 q-rows/block, 4 waves ----------------
__global__ __launch_bounds__(256, 2)
void attn_kernel(const u16* __restrict__ q, const u16* __restrict__ k,
                 const u16* __restrict__ v, u16* __restrict__ out)
{
  __shared__ __align__(16) u16 Ks[64 * 64];      // [s][dh], XOR-swizzled (row&7)
  __shared__ __align__(16) u16 Vt[64 * 64];      // [dh][s], XOR-swizzled ((dh>>3)&7)
  __shared__ __align__(16) u16 Ps[4 * 16 * 64];  // per-wave P [q][s], swizzled ((row>>1)&7)
  const int t = threadIdx.x, w = t >> 6, l = t & 63, lg = l >> 4, lr = l & 15;
  const int qt = blockIdx.x, bh = blockIdx.y;
  const int b = bh >> 4, h = bh & 15;
  const u16* Qp = q + (size_t)bh * T_ * DH_;
  const u16* Kp = k + (size_t)bh * T_ * DH_;
  const u16* Vp = v + (size_t)bh * T_ * DH_;

  const int qrow = qt * 64 + w * 16 + lr;  // A-operand row = lane&15
  const bf16x8 qf0 = *(const bf16x8*)&Qp[(size_t)qrow * DH_ + lg * 8];
  const bf16x8 qf1 = *(const bf16x8*)&Qp[(size_t)qrow * DH_ + 32 + lg * 8];

  float m_run[4], l_run[4];
  f32x4 o[4] = {};
#pragma unroll
  for (int r = 0; r < 4; ++r) { m_run[r] = -1e30f; l_run[r] = 0.f; }

  const int srow = t >> 3;                          // 0..31 per staging issue
  const int kcol = (((t & 7) ^ (srow & 7)) << 3);   // pre-swizzled global source col
  const int vs_dh0 = (t & 7) << 3;

  const int nst = qt + 1;
  for (int st = 0; st < nst; ++st) {
    __syncthreads();
    {  // K tile: global_load_lds, linear LDS dest + swizzled global source
      const u16* g0 = Kp + (size_t)(st * 64 + srow) * DH_ + kcol;
      GLOAD_LDS16(g0,            &Ks[w * 512]);
      GLOAD_LDS16(g0 + 32 * DH_, &Ks[2048 + w * 512]);
    }
#pragma unroll
    for (int i = 0; i < 2; ++i) {  // V tile: reg-staged transpose into Vt[dh][s]
      const int s = i * 32 + srow;
      const uint4 raw = *(const uint4*)&Vp[(size_t)(st * 64 + s) * DH_ + vs_dh0];
      const u16* pr = (const u16*)&raw;
#pragma unroll
      for (int j = 0; j < 8; ++j) {
        const int dh = vs_dh0 + j;
        int byte = (dh << 7) + (s << 1);
        byte ^= ((dh >> 3) & 7) << 4;
        *(u16*)((char*)Vt + byte) = pr[j];
      }
    }
    __syncthreads();

    // scores S[16q][64s] per wave: S = Q * K^T
    f32x4 sa[4] = {};
#pragma unroll
    for (int n = 0; n < 4; ++n) {
      const int sr = n * 16 + lr;               // B-operand col = lane&15
      const int base = (sr << 7) + (lg << 4);
      const int swz = (sr & 7) << 4;
      const bf16x8 b0 = *(const bf16x8*)((const char*)Ks + ((base)      ^ swz));
      const bf16x8 b1 = *(const bf16x8*)((const char*)Ks + ((base + 64) ^ swz));
      sa[n] = mfma16(qf0, b0, sa[n]);
      sa[n] = mfma16(qf1, b1, sa[n]);
    }

    float sc[4][4];
#pragma unroll
    for (int n = 0; n < 4; ++n)
#pragma unroll
      for (int r = 0; r < 4; ++r)
        sc[n][r] = sa[n][r] * 0.03125f;          // 1/sqrt(D)=1/32
    if (st == qt) {                               // diagonal tile causal mask
#pragma unroll
      for (int n = 0; n < 4; ++n)
#pragma unroll
        for (int r = 0; r < 4; ++r)
          if (n * 16 + lr > w * 16 + lg * 4 + r) sc[n][r] = -1e30f;
    }

    float rm[4];
#pragma unroll
    for (int r = 0; r < 4; ++r)
      rm[r] = fmaxf(fmaxf(sc[0][r], sc[1][r]), fmaxf(sc[2][r], sc[3][r]));
#pragma unroll
    for (int msk = 1; msk < 16; msk <<= 1)
#pragma unroll
      for (int r = 0; r < 4; ++r)
        rm[r] = fmaxf(rm[r], __shfl_xor(rm[r], msk));

    float al[4];
#pragma unroll
    for (int r = 0; r < 4; ++r) {
      const float mn = fmaxf(m_run[r], rm[r]);
      al[r] = __expf(m_run[r] - mn);
      m_run[r] = mn;
    }

    float rs[4] = {0.f, 0.f, 0.f, 0.f};
    u16* pw = (u16*)Ps + w * 1024;               // per-wave 2KB region
#pragma unroll
    for (int n = 0; n < 4; ++n) {
#pragma unroll
      for (int r = 0; r < 4; ++r) {
        const float p = __expf(sc[n][r] - m_run[r]);
        rs[r] += p;
        const int prow = lg * 4 + r;             // C row
        int byte = (prow << 7) + ((n * 16 + lr) << 1);
        byte ^= ((prow >> 1) & 7) << 4;
        *(u16*)((char*)pw + byte) = f2bf(p);
      }
    }
#pragma unroll
    for (int msk = 1; msk < 16; msk <<= 1)
#pragma unroll
      for (int r = 0; r < 4; ++r)
        rs[r] += __shfl_xor(rs[r], msk);
#pragma unroll
    for (int r = 0; r < 4; ++r)
      l_run[r] = l_run[r] * al[r] + rs[r];
#pragma unroll
    for (int n = 0; n < 4; ++n)
#pragma unroll
      for (int r = 0; r < 4; ++r)
        o[n][r] *= al[r];

    // O += P * V  (P re-read in A layout; same-wave DS ops are in-order)
#pragma unroll
    for (int ks = 0; ks < 2; ++ks) {
      int abyte = (lr << 7) + (ks << 6) + (lg << 4);
      abyte ^= ((lr >> 1) & 7) << 4;
      const bf16x8 pa = *(const bf16x8*)((const char*)pw + abyte);
#pragma unroll
      for (int n = 0; n < 4; ++n) {
        const int dh = n * 16 + lr;
        int vbyte = (dh << 7) + (ks << 6) + (lg << 4);
        vbyte ^= ((dh >> 3) & 7) << 4;
        const bf16x8 vbf = *(const bf16x8*)((const char*)Vt + vbyte);
        o[n] = mfma16(pa, vbf, o[n]);
      }
    }
  }

  const size_t obase = ((size_t)b * T_) * D_ + (size_t)h * DH_;
#pragma unroll
  for (int n = 0; n < 4; ++n) {
#pragma unroll
    for (int r = 0; r < 4; ++r) {
      const int qg = qt * 64 + w * 16 + lg * 4 + r;
      out[obase + (size_t)qg * D_ + n * 16 + lr] = f2bf(o[n][r] / l_run[r]);
    }
  }
}

// ---------------- host ----------------
extern "C" void kernel_launch(void* const* d_in, const int* in_sizes, int n_in,
                              void* d_out, int out_size, void* d_ws, size_t ws_size,
                              hipStream_t stream) {
  (void)in_sizes; (void)n_in; (void)out_size; (void)ws_size;
  const float* x   = (const float*)d_in[0];
  // d_in[1] = eos_mask (broadcast tril) -> implemented causally, not read
  const float* Wq  = (const float*)d_in[2];
  const float* Wk  = (const float*)d_in[3];
  const float* Wv  = (const float*)d_in[4];
  const float* Wp  = (const float*)d_in[5];
  const float* bp  = (const float*)d_in[6];
  const float* W1  = (const float*)d_in[7];
  const float* b1  = (const float*)d_in[8];
  const float* W2  = (const float*)d_in[9];
  const float* b2  = (const float*)d_in[10];
  const float* g1  = (const float*)d_in[11];
  const float* be1 = (const float*)d_in[12];
  const float* g2  = (const float*)d_in[13];
  const float* be2 = (const float*)d_in[14];

  char* ws = (char*)d_ws;
  float* x1f  = (float*)(ws);                       // 33.5MB f32 [8192][1024]
  u16*   x1b  = (u16*)(ws + (size_t)33554432);      // 16.8MB bf16
  u16*   qb   = (u16*)(ws + (size_t)50331648);      // [B,H,T,DH] bf16
  u16*   kb   = (u16*)(ws + (size_t)67108864);
  u16*   vb   = (u16*)(ws + (size_t)83886080);
  u16*   hb   = (u16*)(ws + (size_t)100663296);     // 67MB bf16 [8192][4096]
  u16*   wqkvb= (u16*)(ws + (size_t)167772160);     // [3072][1024]
  u16*   wpb  = (u16*)(ws + (size_t)174063616);     // [1024][1024]
  u16*   w1b  = (u16*)(ws + (size_t)176160768);     // [4096][1024]
  u16*   w2b  = (u16*)(ws + (size_t)184549376);     // [1024][4096]  (end: 192,937,984)
  // aliases (sequentially safe)
  u16*   attnb = x1b;            // attn out [B,T,D] (x1b dead after QKV GEMM)
  float* x2f   = (float*)kb;     // spans kb+vb (dead after attention)
  float* x3f   = x1f;            // x1f dead after Wp residual
  u16*   x3b   = qb;             // q dead after attention

  dim3 tb(32, 8, 1);
  transpose_cvt<<<dim3(2, 32, 16),  tb, 0, stream>>>(Wq, wqkvb,                    1024, 64);
  transpose_cvt<<<dim3(2, 32, 16),  tb, 0, stream>>>(Wk, wqkvb + (size_t)1048576,  1024, 64);
  transpose_cvt<<<dim3(2, 32, 16),  tb, 0, stream>>>(Wv, wqkvb + (size_t)2097152,  1024, 64);
  transpose_cvt<<<dim3(32, 32, 1),  tb, 0, stream>>>(Wp, wpb, 1024, 1024);
  transpose_cvt<<<dim3(128, 32, 1), tb, 0, stream>>>(W1, w1b, 1024, 4096);
  transpose_cvt<<<dim3(32, 128, 1), tb, 0, stream>>>(W2, w2b, 4096, 1024);

  ln_kernel<<<8192, 256, 0, stream>>>(x, g1, be1, x1f, x1b);

  gemm_kernel<MODE_QKV><<<dim3(24, 64), 256, 0, stream>>>(
      x1b, wqkvb, 8192, 3072, 1024, nullptr, nullptr, nullptr, nullptr, qb, kb, vb);

  attn_kernel<<<dim3(32, 64), 256, 0, stream>>>(qb, kb, vb, attnb);

  gemm_kernel<MODE_WP><<<dim3(8, 64), 256, 0, stream>>>(
      attnb, wpb, 8192, 1024, 1024, bp, x1f, x2f, nullptr, nullptr, nullptr, nullptr);

  ln_kernel<<<8192, 256, 0, stream>>>(x2f, g2, be2, x3f, x3b);

  gemm_kernel<MODE_MLP1><<<dim3(32, 64), 256, 0, stream>>>(
      x3b, w1b, 8192, 4096, 1024, b1, nullptr, nullptr, hb, nullptr, nullptr, nullptr);

  gemm_kernel<MODE_MLP2><<<dim3(8, 64), 256, 0, stream>>>(
      hb, w2b, 8192, 1024, 4096, b2, x3f, (float*)d_out, nullptr, nullptr, nullptr, nullptr);
}

// Round 2
// 433.080 us; speedup vs baseline: 1.4101x; 1.4101x over previous
//
#include <hip/hip_runtime.h>

// Transformer block forward, MI355X gfx950.
// B=4, T=2048, D=1024, H=16, DH=64. bf16 MFMA compute, f32 accum/residuals.

#define B_ 4
#define T_ 2048
#define D_ 1024
#define H_ 16
#define DH_ 64

using u16 = unsigned short;
typedef short bf16x8 __attribute__((ext_vector_type(8)));   // 8 bf16 (4 VGPRs)
typedef float f32x4 __attribute__((ext_vector_type(4)));

#define GLOAD_LDS16(g, l)                                                          \
  __builtin_amdgcn_global_load_lds((const __attribute__((address_space(1))) void*)(g), \
                                   (__attribute__((address_space(3))) void*)(l), 16, 0, 0)

#define CVTPK(d, lo, hi) asm("v_cvt_pk_bf16_f32 %0, %1, %2" : "=v"(d) : "v"(lo), "v"(hi))

__device__ __forceinline__ f32x4 mfma16(bf16x8 a, bf16x8 b, f32x4 c) {
  return __builtin_amdgcn_mfma_f32_16x16x32_bf16(a, b, c, 0, 0, 0);
}

__device__ __forceinline__ u16 f2bf(float f) {  // RNE f32->bf16
  union { float f; unsigned u; } v; v.f = f;
  unsigned r = v.u + 0x7fffu + ((v.u >> 16) & 1u);
  return (u16)(r >> 16);
}

// ---------------- LayerNorm: x[row][1024] -> f32 + bf16 ----------------
__global__ __launch_bounds__(256)
void ln_kernel(const float* __restrict__ x, const float* __restrict__ g,
               const float* __restrict__ be, float* __restrict__ yf,
               u16* __restrict__ yb)
{
  const int row = blockIdx.x;
  const int tid = threadIdx.x;
  const float4 vx = ((const float4*)(x + (size_t)row * D_))[tid];
  float s  = vx.x + vx.y + vx.z + vx.w;
  float s2 = vx.x*vx.x + vx.y*vx.y + vx.z*vx.z + vx.w*vx.w;
#pragma unroll
  for (int m = 1; m < 64; m <<= 1) { s += __shfl_xor(s, m); s2 += __shfl_xor(s2, m); }
  __shared__ float red[8];
  const int w = tid >> 6;
  if ((tid & 63) == 0) { red[w] = s; red[4 + w] = s2; }
  __syncthreads();
  s  = red[0] + red[1] + red[2] + red[3];
  s2 = red[4] + red[5] + red[6] + red[7];
  const float mu   = s * (1.0f / D_);
  const float rstd = rsqrtf(s2 * (1.0f / D_) - mu * mu + 1e-5f);
  const float4 gg = ((const float4*)g)[tid];
  const float4 bb = ((const float4*)be)[tid];
  float4 y;
  y.x = (vx.x - mu) * rstd * gg.x + bb.x;
  y.y = (vx.y - mu) * rstd * gg.y + bb.y;
  y.z = (vx.z - mu) * rstd * gg.z + bb.z;
  y.w = (vx.w - mu) * rstd * gg.w + bb.w;
  ((float4*)(yf + (size_t)row * D_))[tid] = y;
  ushort4 pk;
  pk.x = f2bf(y.x); pk.y = f2bf(y.y); pk.z = f2bf(y.z); pk.w = f2bf(y.w);
  ((ushort4*)(yb + (size_t)row * D_))[tid] = pk;
}

// ------------- transpose + cvt: in f32 [R][C] -> out bf16 [C][R], per z-matrix -------------
__global__ __launch_bounds__(256)
void transpose_cvt(const float* __restrict__ in, u16* __restrict__ out, int R, int C)
{
  __shared__ float tile[32][33];
  const int c0 = blockIdx.x * 32, r0 = blockIdx.y * 32;
  const float* ip = in + (size_t)blockIdx.z * R * C;
  u16* op = out + (size_t)blockIdx.z * R * C;
  const int tx = threadIdx.x, ty = threadIdx.y;  // 32 x 8
#pragma unroll
  for (int j = 0; j < 4; ++j)
    tile[ty + j * 8][tx] = ip[(size_t)(r0 + ty + j * 8) * C + (c0 + tx)];
  __syncthreads();
#pragma unroll
  for (int j = 0; j < 4; ++j)
    op[(size_t)(c0 + ty + j * 8) * R + (r0 + tx)] = f2bf(tile[tx][ty + j * 8]);
}

// ---------------- GEMM: C[M,N] = A[M,K](bf16) * Bt[N,K]^T(bf16), m97 structure ----------------
#define MODE_QKV 0
#define MODE_WP 1
#define MODE_MLP1 2
#define MODE_MLP2 3

template<int MODE>
__global__ __launch_bounds__(256, 2)
void gemm_kernel(const u16* __restrict__ A, const u16* __restrict__ Bt,
                 int M, int N, int K,
                 const float* __restrict__ bias, const float* __restrict__ resid,
                 float* __restrict__ outf, u16* __restrict__ outb,
                 u16* __restrict__ qo, u16* __restrict__ ko, u16* __restrict__ vo)
{
  __shared__ __align__(16) u16 As[128 * 32];
  __shared__ __align__(16) u16 Bs[128 * 32];
  const int t = threadIdx.x;
  const int w = t >> 6, l = t & 63, lg = l >> 4, lr = l & 15;
  const int wr = w >> 1, wc = w & 1;
  const int bm0 = blockIdx.y * 128, bn0 = blockIdx.x * 128;

  f32x4 acc[4][4] = {};

  const int srcCol = (t & 3) << 3;
  const u16* gA = A  + (size_t)(bm0 + (t >> 2)) * K + srcCol;
  const u16* gB = Bt + (size_t)(bn0 + (t >> 2)) * K + srcCol;
  u16* lA = &As[w * 512];
  u16* lB = &Bs[w * 512];
  const size_t skip = (size_t)64 * K;

  for (int kt = 0; kt < K; kt += 32) {
    __syncthreads();
    GLOAD_LDS16(gA + kt,        lA);
    GLOAD_LDS16(gA + skip + kt, lA + 2048);
    GLOAD_LDS16(gB + kt,        lB);
    GLOAD_LDS16(gB + skip + kt, lB + 2048);
    __syncthreads();
    bf16x8 af[4], bfv[4];
#pragma unroll
    for (int m = 0; m < 4; ++m)
      af[m] = *(const bf16x8*)&As[(wr * 64 + m * 16 + lr) * 32 + lg * 8];
#pragma unroll
    for (int n = 0; n < 4; ++n)
      bfv[n] = *(const bf16x8*)&Bs[(wc * 64 + n * 16 + lr) * 32 + lg * 8];
#pragma unroll
    for (int m = 0; m < 4; ++m)
#pragma unroll
      for (int n = 0; n < 4; ++n)
        acc[m][n] = mfma16(af[m], bfv[n], acc[m][n]);
  }

#pragma unroll
  for (int m = 0; m < 4; ++m) {
#pragma unroll
    for (int n = 0; n < 4; ++n) {
#pragma unroll
      for (int r = 0; r < 4; ++r) {
        const int row = bm0 + wr * 64 + m * 16 + lg * 4 + r;
        const int col = bn0 + wc * 64 + n * 16 + lr;
        float v = acc[m][n][r];
        if constexpr (MODE == MODE_QKV) {
          const int sel = col >> 10, hh = (col >> 6) & 15, dh = col & 63;
          const int bi = row >> 11, tt = row & 2047;
          u16* dst = (sel == 0) ? qo : (sel == 1) ? ko : vo;
          dst[(((size_t)bi * H_ + hh) * T_ + tt) * DH_ + dh] = f2bf(v);
        } else if constexpr (MODE == MODE_WP) {
          outf[(size_t)row * N + col] = v + bias[col] + resid[(size_t)row * N + col];
        } else if constexpr (MODE == MODE_MLP1) {
          v += bias[col];
          outb[(size_t)row * N + col] = f2bf(v > 0.f ? v : 0.f);
        } else {
          outf[(size_t)row * N + col] = v + bias[col] + resid[(size_t)row * N + col];
        }
      }
    }
  }
}

// ---------------- Flash attention v2: pipelined, in-register P, causal ----------------
// 64 q-rows/block, 4 waves (16 q each). Swapped QK^T: lane owns q=lane&15's scores.
__global__ __launch_bounds__(256, 2)
void attn_kernel(const u16* __restrict__ q, const u16* __restrict__ k,
                 const u16* __restrict__ v, u16* __restrict__ out)
{
  __shared__ __align__(16) u16 Ks[2][4096];   // [s][dh], XOR-swizzled ((s&7)<<4)
  __shared__ __align__(16) u16 Vt[2][4096];   // [dh][s], XOR-swizzled (((dh&7)^((dh>>3)&7))<<4)
  const int t = threadIdx.x, w = t >> 6, l = t & 63, lg = l >> 4, lr = l & 15;
  const int qt = 31 - (blockIdx.x >> 6);      // longest blocks first
  const int bh = blockIdx.x & 63;
  const int b = bh >> 4, h = bh & 15;
  const u16* Qp = q + (size_t)bh * T_ * DH_;
  const u16* Kp = k + (size_t)bh * T_ * DH_;
  const u16* Vp = v + (size_t)bh * T_ * DH_;

  const int qrow = qt * 64 + w * 16 + lr;     // this lane's q row (softmax domain)
  const bf16x8 qf0 = *(const bf16x8*)&Qp[(size_t)qrow * DH_ + lg * 8];
  const bf16x8 qf1 = *(const bf16x8*)&Qp[(size_t)qrow * DH_ + 32 + lg * 8];

  const int srow = t >> 3;                    // staging row 0..31
  const int kcol = (((t & 7) ^ (srow & 7)) << 3);
  const int vdh0 = (t & 7) << 3;
  const u16* Kg = Kp + (size_t)srow * DH_ + kcol;
  const u16* Vg = Vp + (size_t)srow * DH_ + vdh0;

  float m_run = -1e30f, l_run = 0.f;
  f32x4 o[4] = {};
  const float SC2 = 0.03125f * 1.44269504f;   // (1/sqrt(D)) * log2(e)
  const float THR2 = 11.5416f;                // 8 * log2(e)

  auto writeV = [&](int buf, uint4 va, uint4 vb) {
    const u16* pa = (const u16*)&va;
    const u16* pb = (const u16*)&vb;
    char* base = (char*)&Vt[buf][0];
#pragma unroll
    for (int j = 0; j < 8; ++j) {
      const int dh = vdh0 + j;
      const int swz = (((dh & 7) ^ ((dh >> 3) & 7)) << 4);
      *(u16*)(base + (((dh << 7) + (srow << 1)) ^ swz)) = pa[j];
      *(u16*)(base + (((dh << 7) + ((32 + srow) << 1)) ^ swz)) = pb[j];
    }
  };

  // prologue: stage tile 0 into buffer 0
  GLOAD_LDS16(Kg,            &Ks[0][w * 512]);
  GLOAD_LDS16(Kg + 32 * DH_, &Ks[0][2048 + w * 512]);
  {
    uint4 v0 = *(const uint4*)Vg;
    uint4 v1 = *(const uint4*)(Vg + 32 * DH_);
    writeV(0, v0, v1);
  }
  __syncthreads();

  const int nst = qt + 1;
  for (int st = 0; st < nst; ++st) {
    const int cur = st & 1, nxt = cur ^ 1;
    uint4 vA, vB;
    const bool pf = (st + 1 < nst);
    if (pf) {  // prefetch next tile: K -> LDS (async), V -> regs
      const u16* kg = Kg + (size_t)(st + 1) * 64 * DH_;
      GLOAD_LDS16(kg,            &Ks[nxt][w * 512]);
      GLOAD_LDS16(kg + 32 * DH_, &Ks[nxt][2048 + w * 512]);
      vA = *(const uint4*)(Vg + (size_t)(st + 1) * 64 * DH_);
      vB = *(const uint4*)(Vg + (size_t)(st + 1) * 64 * DH_ + 32 * DH_);
    }

    // S^T = K * Q^T : lane holds S[s = n*16+lg*4+r][q = lr]
    f32x4 sa[4] = {};
    const char* kb = (const char*)&Ks[cur][0];
    __builtin_amdgcn_s_setprio(1);
#pragma unroll
    for (int n = 0; n < 4; ++n) {
      const int sr = n * 16 + lr;
      const int base = (sr << 7) + (lg << 4);
      const int swz = (sr & 7) << 4;
      const bf16x8 b0 = *(const bf16x8*)(kb + (base ^ swz));
      const bf16x8 b1 = *(const bf16x8*)(kb + ((base + 64) ^ swz));
      sa[n] = mfma16(b0, qf0, sa[n]);
      sa[n] = mfma16(b1, qf1, sa[n]);
    }
    __builtin_amdgcn_s_setprio(0);

    // online softmax in log2 domain, q = lr per lane
    float sc[4][4];
    float rm = -1e30f;
#pragma unroll
    for (int n = 0; n < 4; ++n)
#pragma unroll
      for (int r = 0; r < 4; ++r) {
        float x = sa[n][r] * SC2;
        if (st == qt && (st * 64 + n * 16 + lg * 4 + r) > qrow) x = -1e30f;
        sc[n][r] = x;
        rm = fmaxf(rm, x);
      }
    rm = fmaxf(rm, __shfl_xor(rm, 16));
    rm = fmaxf(rm, __shfl_xor(rm, 32));
    const bool noresc = __all(rm <= m_run + THR2);
    if (!noresc) {
      const float mnew = fmaxf(m_run, rm);
      const float al = exp2f(m_run - mnew);
      m_run = mnew;
      l_run *= al;
      const float alr0 = __shfl(al, lg * 4 + 0);
      const float alr1 = __shfl(al, lg * 4 + 1);
      const float alr2 = __shfl(al, lg * 4 + 2);
      const float alr3 = __shfl(al, lg * 4 + 3);
#pragma unroll
      for (int n = 0; n < 4; ++n) {
        o[n][0] *= alr0; o[n][1] *= alr1; o[n][2] *= alr2; o[n][3] *= alr3;
      }
    }
    float p[4][4];
    float rs = 0.f;
#pragma unroll
    for (int n = 0; n < 4; ++n)
#pragma unroll
      for (int r = 0; r < 4; ++r) {
        p[n][r] = exp2f(sc[n][r] - m_run);
        rs += p[n][r];
      }
    rs += __shfl_xor(rs, 16);
    rs += __shfl_xor(rs, 32);
    l_run += rs;

    // pack P to bf16 pairs: pk[n] = {(r0,r1),(r2,r3)} for s-block n
    unsigned pk0a, pk0b, pk1a, pk1b, pk2a, pk2b, pk3a, pk3b;
    CVTPK(pk0a, p[0][0], p[0][1]); CVTPK(pk0b, p[0][2], p[0][3]);
    CVTPK(pk1a, p[1][0], p[1][1]); CVTPK(pk1b, p[1][2], p[1][3]);
    CVTPK(pk2a, p[2][0], p[2][1]); CVTPK(pk2b, p[2][2], p[2][3]);
    CVTPK(pk3a, p[3][0], p[3][1]); CVTPK(pk3b, p[3][2], p[3][3]);

    // redistribute to PV A-fragments: lane needs P[q=lr][s = ks*32 + lg*8 + j]
    const int srcA = lr + ((l >> 4) & 1) * 32;   // source lane for j=0..3
    const int srcB = srcA + 16;                  // source lane for j=4..7
    const bool hi = (l >> 5) & 1;                // selects n-block within pair
    union { uint4 u; bf16x8 v8; } f0, f1;
    {
      const unsigned xA0 = __shfl(pk0a, srcA), xA1 = __shfl(pk0b, srcA);
      const unsigned yA0 = __shfl(pk1a, srcA), yA1 = __shfl(pk1b, srcA);
      const unsigned xB0 = __shfl(pk0a, srcB), xB1 = __shfl(pk0b, srcB);
      const unsigned yB0 = __shfl(pk1a, srcB), yB1 = __shfl(pk1b, srcB);
      f0.u.x = hi ? yA0 : xA0; f0.u.y = hi ? yA1 : xA1;
      f0.u.z = hi ? yB0 : xB0; f0.u.w = hi ? yB1 : xB1;
    }
    {
      const unsigned xA0 = __shfl(pk2a, srcA), xA1 = __shfl(pk2b, srcA);
      const unsigned yA0 = __shfl(pk3a, srcA), yA1 = __shfl(pk3b, srcA);
      const unsigned xB0 = __shfl(pk2a, srcB), xB1 = __shfl(pk2b, srcB);
      const unsigned yB0 = __shfl(pk3a, srcB), yB1 = __shfl(pk3b, srcB);
      f1.u.x = hi ? yA0 : xA0; f1.u.y = hi ? yA1 : xA1;
      f1.u.z = hi ? yB0 : xB0; f1.u.w = hi ? yB1 : xB1;
    }

    // O += P * V
    const char* vbase = (const char*)&Vt[cur][0];
    __builtin_amdgcn_s_setprio(1);
#pragma unroll
    for (int ks = 0; ks < 2; ++ks) {
      const bf16x8 pa = ks ? f1.v8 : f0.v8;
#pragma unroll
      for (int n = 0; n < 4; ++n) {
        const int dh = n * 16 + lr;
        int vbyte = (dh << 7) + (ks << 6) + (lg << 4);
        vbyte ^= (((dh & 7) ^ ((dh >> 3) & 7)) << 4);
        const bf16x8 vbf = *(const bf16x8*)(vbase + vbyte);
        o[n] = mfma16(pa, vbf, o[n]);
      }
    }
    __builtin_amdgcn_s_setprio(0);

    if (pf) writeV(nxt, vA, vB);
    __syncthreads();
  }

  const size_t obase = ((size_t)b * T_) * D_ + (size_t)h * DH_;
  float li[4];
  li[0] = 1.0f / __shfl(l_run, lg * 4 + 0);
  li[1] = 1.0f / __shfl(l_run, lg * 4 + 1);
  li[2] = 1.0f / __shfl(l_run, lg * 4 + 2);
  li[3] = 1.0f / __shfl(l_run, lg * 4 + 3);
#pragma unroll
  for (int n = 0; n < 4; ++n) {
#pragma unroll
    for (int r = 0; r < 4; ++r) {
      const int qg = qt * 64 + w * 16 + lg * 4 + r;
      out[obase + (size_t)qg * D_ + n * 16 + lr] = f2bf(o[n][r] * li[r]);
    }
  }
}

// ---------------- host ----------------
extern "C" void kernel_launch(void* const* d_in, const int* in_sizes, int n_in,
                              void* d_out, int out_size, void* d_ws, size_t ws_size,
                              hipStream_t stream) {
  (void)in_sizes; (void)n_in; (void)out_size; (void)ws_size;
  const float* x   = (const float*)d_in[0];
  const float* Wq  = (const float*)d_in[2];
  const float* Wk  = (const float*)d_in[3];
  const float* Wv  = (const float*)d_in[4];
  const float* Wp  = (const float*)d_in[5];
  const float* bp  = (const float*)d_in[6];
  const float* W1  = (const float*)d_in[7];
  const float* b1  = (const float*)d_in[8];
  const float* W2  = (const float*)d_in[9];
  const float* b2  = (const float*)d_in[10];
  const float* g1  = (const float*)d_in[11];
  const float* be1 = (const float*)d_in[12];
  const float* g2  = (const float*)d_in[13];
  const float* be2 = (const float*)d_in[14];

  char* ws = (char*)d_ws;
  float* x1f  = (float*)(ws);
  u16*   x1b  = (u16*)(ws + (size_t)33554432);
  u16*   qb   = (u16*)(ws + (size_t)50331648);
  u16*   kb   = (u16*)(ws + (size_t)67108864);
  u16*   vb   = (u16*)(ws + (size_t)83886080);
  u16*   hb   = (u16*)(ws + (size_t)100663296);
  u16*   wqkvb= (u16*)(ws + (size_t)167772160);
  u16*   wpb  = (u16*)(ws + (size_t)174063616);
  u16*   w1b  = (u16*)(ws + (size_t)176160768);
  u16*   w2b  = (u16*)(ws + (size_t)184549376);
  u16*   attnb = x1b;
  float* x2f   = (float*)kb;
  float* x3f   = x1f;
  u16*   x3b   = qb;

  dim3 tb(32, 8, 1);
  transpose_cvt<<<dim3(2, 32, 16),  tb, 0, stream>>>(Wq, wqkvb,                    1024, 64);
  transpose_cvt<<<dim3(2, 32, 16),  tb, 0, stream>>>(Wk, wqkvb + (size_t)1048576,  1024, 64);
  transpose_cvt<<<dim3(2, 32, 16),  tb, 0, stream>>>(Wv, wqkvb + (size_t)2097152,  1024, 64);
  transpose_cvt<<<dim3(32, 32, 1),  tb, 0, stream>>>(Wp, wpb, 1024, 1024);
  transpose_cvt<<<dim3(128, 32, 1), tb, 0, stream>>>(W1, w1b, 1024, 4096);
  transpose_cvt<<<dim3(32, 128, 1), tb, 0, stream>>>(W2, w2b, 4096, 1024);

  ln_kernel<<<8192, 256, 0, stream>>>(x, g1, be1, x1f, x1b);

  gemm_kernel<MODE_QKV><<<dim3(24, 64), 256, 0, stream>>>(
      x1b, wqkvb, 8192, 3072, 1024, nullptr, nullptr, nullptr, nullptr, qb, kb, vb);

  attn_kernel<<<dim3(2048), 256, 0, stream>>>(qb, kb, vb, attnb);

  gemm_kernel<MODE_WP><<<dim3(8, 64), 256, 0, stream>>>(
      attnb, wpb, 8192, 1024, 1024, bp, x1f, x2f, nullptr, nullptr, nullptr, nullptr);

  ln_kernel<<<8192, 256, 0, stream>>>(x2f, g2, be2, x3f, x3b);

  gemm_kernel<MODE_MLP1><<<dim3(32, 64), 256, 0, stream>>>(
      x3b, w1b, 8192, 4096, 1024, b1, nullptr, nullptr, hb, nullptr, nullptr, nullptr);

  gemm_kernel<MODE_MLP2><<<dim3(8, 64), 256, 0, stream>>>(
      hb, w2b, 8192, 1024, 4096, b2, x3f, (float*)d_out, nullptr, nullptr, nullptr, nullptr);
}